// Round 7
// baseline (234.612 us; speedup 1.0000x reference)
//
#include <hip/hip_runtime.h>
#include <hip/hip_fp16.h>

// GCN encoder: out = A' relu(A' (x W1) + b1) W2 + b2, A' = D^-1/2 (A+I) D^-1/2
// Round 14: R13 passed (233us); aggs remain the largest interiors (by elimination)
// and are concurrency-bound (R12: occupancy cut -> slower). Remaining waste: each
// edge row (32B) fetched as 8x4B lane-loads = 200K wave VMEM instrs/agg, only
// 4B/lane in flight per outstanding-load slot.
// CHANGE: aggs go 2 threads/node with 16B float4 row-half gathers — same bytes,
// 4x fewer gather instructions, 4x bytes-in-flight per wave slot; one coalesced
// 16B store per thread. ~40 VGPR, occupancy unchanged. All else identical to R13.
// Algebra: g1 = f16(f16(x@W1)*dinv); p[d] = dinv_d*(g1_d + sum_s g1_s).

#define NN 100000
#define NE 1600000
#define FI 128
#define FH 16
#define CB 64                  // nodes per bucket
#define NB 1563                // ceil(NN/64); NB*64 = 100032
#define GC 512                 // edge chunks
#define CHUNK 3125             // NE/GC exactly
#define SCB 16                 // buckets per scan block

__device__ __forceinline__ float fc(const float4& v, int i) {
    return i == 0 ? v.x : i == 1 ? v.y : i == 2 ? v.z : v.w;
}

// ---------- fat kernel: count (blocks [0,GC)) + gemm1 (blocks [GC, GC+391)) ----------
// hist layout: hist[c * NB + b]  (chunk-major -> coalesced in count/scatter)
// gemm1: g1 = f16(x @ W1), unscaled (bsort applies dinv in-place later).
__global__ __launch_bounds__(256) void k_count_gemm1(const int* __restrict__ dst,
                                                     int* __restrict__ hist,
                                                     const float* __restrict__ x,
                                                     const float* __restrict__ W1,
                                                     __half2* __restrict__ g1) {
    __shared__ __align__(16) float w[FI * FH];        // 8KB; count half reuses as int h[NB]
    if (blockIdx.x < GC) {
        int* h = (int*)w;                              // NB ints = 6252B <= 8192B
        for (int i = threadIdx.x; i < NB; i += 256) h[i] = 0;
        __syncthreads();
        int base = blockIdx.x * CHUNK;
        for (int i = base + threadIdx.x; i < base + CHUNK; i += 256)
            atomicAdd(&h[dst[i] >> 6], 1);
        __syncthreads();
        for (int b = threadIdx.x; b < NB; b += 256)
            hist[blockIdx.x * NB + b] = h[b];
    } else {
        // ---- gemm1: 256 nodes/block, thread = 4 nodes x 4 feats ----
        float4* w4s = (float4*)w;
        w4s[threadIdx.x] = ((const float4*)W1)[threadIdx.x];
        w4s[threadIdx.x + 256] = ((const float4*)W1)[threadIdx.x + 256];
        __syncthreads();
        int fg = threadIdx.x & 3;
        int ng = threadIdx.x >> 2;
        int r0 = (blockIdx.x - GC) * 256 + ng * 4;
        const float4* x4 = (const float4*)x;
        int rr[4]; bool val[4];
        #pragma unroll
        for (int i = 0; i < 4; ++i) {
            val[i] = (r0 + i < NN);
            rr[i] = val[i] ? r0 + i : NN - 1;
        }
        float acc[4][4];
        #pragma unroll
        for (int i = 0; i < 4; ++i)
            #pragma unroll
            for (int j = 0; j < 4; ++j) acc[i][j] = 0.f;
        #pragma unroll 2
        for (int k4 = 0; k4 < 32; ++k4) {
            float4 xv[4];
            #pragma unroll
            for (int i = 0; i < 4; ++i) xv[i] = x4[rr[i] * 32 + k4];
            #pragma unroll
            for (int kk = 0; kk < 4; ++kk) {
                float4 wv = w4s[(k4 * 4 + kk) * 4 + fg];
                #pragma unroll
                for (int i = 0; i < 4; ++i) {
                    float xk = fc(xv[i], kk);
                    acc[i][0] += xk * wv.x; acc[i][1] += xk * wv.y;
                    acc[i][2] += xk * wv.z; acc[i][3] += xk * wv.w;
                }
            }
        }
        #pragma unroll
        for (int i = 0; i < 4; ++i) if (val[i]) {
            g1[rr[i] * 8 + fg * 2]     = __floats2half2_rn(acc[i][0], acc[i][1]);
            g1[rr[i] * 8 + fg * 2 + 1] = __floats2half2_rn(acc[i][2], acc[i][3]);
        }
    }
}

// per-bucket exclusive scan over chunks; 16 buckets/block, coalesced loads.
__global__ __launch_bounds__(256) void k_scan_chunks(int* __restrict__ hist,
                                                     int* __restrict__ totals) {
    __shared__ int s[GC * SCB];                       // 32 KB
    int b0 = blockIdx.x * SCB;
    int o[GC * SCB / 256];
    #pragma unroll
    for (int r = 0; r < GC * SCB / 256; ++r) {
        int idx = r * 256 + threadIdx.x;
        int c = idx >> 4, bl = idx & (SCB - 1), b = b0 + bl;
        int v = (b < NB) ? hist[c * NB + b] : 0;
        s[idx] = v;
        o[r] = v;
    }
    __syncthreads();
    for (int off = 1; off < GC; off <<= 1) {
        int t[GC * SCB / 256];
        #pragma unroll
        for (int r = 0; r < GC * SCB / 256; ++r) {
            int idx = r * 256 + threadIdx.x;
            int c = idx >> 4;
            t[r] = (c >= off) ? s[idx - off * SCB] : 0;
        }
        __syncthreads();
        #pragma unroll
        for (int r = 0; r < GC * SCB / 256; ++r) {
            int idx = r * 256 + threadIdx.x;
            s[idx] += t[r];
        }
        __syncthreads();
    }
    #pragma unroll
    for (int r = 0; r < GC * SCB / 256; ++r) {
        int idx = r * 256 + threadIdx.x;
        int c = idx >> 4, bl = idx & (SCB - 1), b = b0 + bl;
        if (b < NB) {
            hist[c * NB + b] = s[idx] - o[r];          // exclusive within bucket
            if (c == GC - 1) totals[b] = s[idx];       // bucket total
        }
    }
}

// bucket scan + zero g1 sentinel row NN.
__global__ __launch_bounds__(1024) void k_scan_buckets(const int* __restrict__ totals,
                                                       int* __restrict__ bucketStart,
                                                       __half2* __restrict__ g1) {
    __shared__ int s[1024];
    int tid = threadIdx.x;
    if (tid < 8) g1[NN * 8 + tid] = __floats2half2_rn(0.f, 0.f);
    int i0 = 2 * tid, i1 = i0 + 1;
    int a = (i0 < NB) ? totals[i0] : 0;
    int b = (i1 < NB) ? totals[i1] : 0;
    s[tid] = a + b;
    __syncthreads();
    #pragma unroll
    for (int off = 1; off < 1024; off <<= 1) {
        int t = (tid >= off) ? s[tid - off] : 0;
        __syncthreads();
        s[tid] += t;
        __syncthreads();
    }
    int excl = s[tid] - (a + b);
    if (i0 < NB) bucketStart[i0] = excl;
    if (i1 < NB) bucketStart[i1] = excl + a;
    if (tid == 0) bucketStart[NB] = NE;
}

__global__ __launch_bounds__(256) void k_scatter(const int* __restrict__ src,
                                                 const int* __restrict__ dst,
                                                 const int* __restrict__ hist,
                                                 const int* __restrict__ bucketStart,
                                                 int* __restrict__ packed) {
    __shared__ int cur[NB];
    for (int b = threadIdx.x; b < NB; b += 256)
        cur[b] = hist[blockIdx.x * NB + b] + bucketStart[b];   // addback folded in
    __syncthreads();
    int base = blockIdx.x * CHUNK;
    for (int i = base + threadIdx.x; i < base + CHUNK; i += 256) {
        int d = dst[i];
        int pos = atomicAdd(&cur[d >> 6], 1);
        packed[pos] = src[i] | ((d & 63) << 17);   // src < 2^17, local node in [0,64)
    }
}

// per-bucket sort -> PADDED CSR (mult-of-4 rows, sentinel NN) + rowSE + dinv;
// then scale g1 rows of this bucket in-place by dinv.
// Padded bucket base: align4(bucketStart[b] + 200*b) — capacity >= total+197 >= padded.
__global__ __launch_bounds__(256) void k_bsort(const int* __restrict__ packed,
                                               const int* __restrict__ bucketStart,
                                               int* __restrict__ csr,
                                               int2* __restrict__ rowSE,
                                               float* __restrict__ dinv,
                                               __half2* __restrict__ g1) {
    __shared__ int cnt[CB];
    __shared__ int rsp[CB];    // inclusive prefix of padded counts
    __shared__ int cur[CB];
    __shared__ float dvs[CB];
    int b = blockIdx.x;
    if (threadIdx.x < CB) cnt[threadIdx.x] = 0;
    __syncthreads();
    int s0 = bucketStart[b], s1 = bucketStart[b + 1];
    for (int i = s0 + threadIdx.x; i < s1; i += 256)
        atomicAdd(&cnt[(packed[i] >> 17) & 63], 1);
    __syncthreads();
    int c = 0, cp = 0;
    if (threadIdx.x < CB) {
        c = cnt[threadIdx.x];
        cp = (c + 3) & ~3;
        rsp[threadIdx.x] = cp;
    }
    __syncthreads();
    #pragma unroll
    for (int off = 1; off < CB; off <<= 1) {
        int t = 0;
        if (threadIdx.x < CB && threadIdx.x >= off) t = rsp[threadIdx.x - off];
        __syncthreads();
        if (threadIdx.x < CB) rsp[threadIdx.x] += t;
        __syncthreads();
    }
    int base = (s0 + 200 * b + 3) & ~3;
    if (threadIdx.x < CB) {
        int start = base + rsp[threadIdx.x] - cp;      // exclusive padded prefix
        cur[threadIdx.x] = start;
        float dv = rsqrtf((float)(c + 1));
        dvs[threadIdx.x] = dv;
        int node = b * CB + threadIdx.x;
        if (node < NN) {
            rowSE[node] = make_int2(start, start + cp);
            dinv[node] = dv;
        }
    }
    __syncthreads();
    for (int i = s0 + threadIdx.x; i < s1; i += 256) {
        int pk = packed[i];
        int pos = atomicAdd(&cur[(pk >> 17) & 63], 1);
        csr[pos] = pk & 131071;
    }
    __syncthreads();
    if (threadIdx.x < CB) {
        int end = cur[threadIdx.x];                    // = start + c
        int endp = end + (cp - c);
        for (int p = end; p < endp; ++p) csr[p] = NN;  // sentinel -> zero row
    }
    // ---- scale g1 rows of this bucket: half2 range [b*512, b*512+512) ----
    int gbase = b * (CB * 8);
    #pragma unroll
    for (int r = 0; r < 2; ++r) {
        int i = r * 256 + threadIdx.x;
        int gi = gbase + i;
        if (gi < NN * 8) {
            float dv = dvs[i >> 3];
            float2 f = __half22float2(g1[gi]);
            g1[gi] = __floats2half2_rn(f.x * dv, f.y * dv);
        }
    }
}

// agg layer 1: 2 threads/node, 16B float4 row-half gathers, branch-free padded loop.
// g1 pre-scaled: g2 = f16(relu(dv*(g1_d + sum_s g1_s) + b1) * dv)
__global__ __launch_bounds__(256) void k_agg1(const int* __restrict__ csr,
                                              const int2* __restrict__ rowSE,
                                              const __half2* __restrict__ g1,
                                              const float* __restrict__ dinv,
                                              const float* __restrict__ b1,
                                              __half2* __restrict__ g2) {
    if (blockIdx.x == 0 && threadIdx.x < 8)
        g2[NN * 8 + threadIdx.x] = __floats2half2_rn(0.f, 0.f);   // zero sentinel row
    int gid = blockIdx.x * 256 + threadIdx.x;
    int node = gid >> 1, hf = gid & 1;     // hf = which 16B half of the 32B row
    if (node >= NN) return;
    int2 se = rowSE[node];
    const float4* g14 = (const float4*)g1;                  // row = 2 float4
    float4 sv = g14[node * 2 + hf];                         // self-loop term
    float2 a0 = __half22float2(*(const __half2*)&sv.x);
    float2 a1 = __half22float2(*(const __half2*)&sv.y);
    float2 a2 = __half22float2(*(const __half2*)&sv.z);
    float2 a3 = __half22float2(*(const __half2*)&sv.w);
    for (int e = se.x; e < se.y; e += 4) {
        int4 i4 = *(const int4*)(csr + e);
        float4 v0 = g14[i4.x * 2 + hf];
        float4 v1 = g14[i4.y * 2 + hf];
        float4 v2 = g14[i4.z * 2 + hf];
        float4 v3 = g14[i4.w * 2 + hf];
        float2 p0 = __half22float2(*(const __half2*)&v0.x);
        float2 p1 = __half22float2(*(const __half2*)&v1.x);
        float2 p2 = __half22float2(*(const __half2*)&v2.x);
        float2 p3 = __half22float2(*(const __half2*)&v3.x);
        a0.x += (p0.x + p1.x) + (p2.x + p3.x);
        a0.y += (p0.y + p1.y) + (p2.y + p3.y);
        p0 = __half22float2(*(const __half2*)&v0.y);
        p1 = __half22float2(*(const __half2*)&v1.y);
        p2 = __half22float2(*(const __half2*)&v2.y);
        p3 = __half22float2(*(const __half2*)&v3.y);
        a1.x += (p0.x + p1.x) + (p2.x + p3.x);
        a1.y += (p0.y + p1.y) + (p2.y + p3.y);
        p0 = __half22float2(*(const __half2*)&v0.z);
        p1 = __half22float2(*(const __half2*)&v1.z);
        p2 = __half22float2(*(const __half2*)&v2.z);
        p3 = __half22float2(*(const __half2*)&v3.z);
        a2.x += (p0.x + p1.x) + (p2.x + p3.x);
        a2.y += (p0.y + p1.y) + (p2.y + p3.y);
        p0 = __half22float2(*(const __half2*)&v0.w);
        p1 = __half22float2(*(const __half2*)&v1.w);
        p2 = __half22float2(*(const __half2*)&v2.w);
        p3 = __half22float2(*(const __half2*)&v3.w);
        a3.x += (p0.x + p1.x) + (p2.x + p3.x);
        a3.y += (p0.y + p1.y) + (p2.y + p3.y);
    }
    float dv = dinv[node];
    const float4* b14 = (const float4*)b1;                  // 16 floats = 4 float4
    float4 bb0 = b14[hf * 2], bb1 = b14[hf * 2 + 1];
    float4 o;
    *(__half2*)&o.x = __floats2half2_rn(fmaxf(dv * a0.x + bb0.x, 0.f) * dv,
                                        fmaxf(dv * a0.y + bb0.y, 0.f) * dv);
    *(__half2*)&o.y = __floats2half2_rn(fmaxf(dv * a1.x + bb0.z, 0.f) * dv,
                                        fmaxf(dv * a1.y + bb0.w, 0.f) * dv);
    *(__half2*)&o.z = __floats2half2_rn(fmaxf(dv * a2.x + bb1.x, 0.f) * dv,
                                        fmaxf(dv * a2.y + bb1.y, 0.f) * dv);
    *(__half2*)&o.w = __floats2half2_rn(fmaxf(dv * a3.x + bb1.z, 0.f) * dv,
                                        fmaxf(dv * a3.y + bb1.w, 0.f) * dv);
    ((float4*)g2)[node * 2 + hf] = o;
}

// agg layer 2: same 2thr/node shape; p2 = f16(dv*(g2_d + sum_s g2_s))
__global__ __launch_bounds__(256) void k_agg2(const int* __restrict__ csr,
                                              const int2* __restrict__ rowSE,
                                              const __half2* __restrict__ g2,
                                              const float* __restrict__ dinv,
                                              __half2* __restrict__ p2h) {
    int gid = blockIdx.x * 256 + threadIdx.x;
    int node = gid >> 1, hf = gid & 1;
    if (node >= NN) return;
    int2 se = rowSE[node];
    const float4* g24 = (const float4*)g2;
    float4 sv = g24[node * 2 + hf];                         // self-loop term
    float2 a0 = __half22float2(*(const __half2*)&sv.x);
    float2 a1 = __half22float2(*(const __half2*)&sv.y);
    float2 a2 = __half22float2(*(const __half2*)&sv.z);
    float2 a3 = __half22float2(*(const __half2*)&sv.w);
    for (int e = se.x; e < se.y; e += 4) {
        int4 i4 = *(const int4*)(csr + e);
        float4 v0 = g24[i4.x * 2 + hf];
        float4 v1 = g24[i4.y * 2 + hf];
        float4 v2 = g24[i4.z * 2 + hf];
        float4 v3 = g24[i4.w * 2 + hf];
        float2 p0 = __half22float2(*(const __half2*)&v0.x);
        float2 p1 = __half22float2(*(const __half2*)&v1.x);
        float2 p2 = __half22float2(*(const __half2*)&v2.x);
        float2 p3 = __half22float2(*(const __half2*)&v3.x);
        a0.x += (p0.x + p1.x) + (p2.x + p3.x);
        a0.y += (p0.y + p1.y) + (p2.y + p3.y);
        p0 = __half22float2(*(const __half2*)&v0.y);
        p1 = __half22float2(*(const __half2*)&v1.y);
        p2 = __half22float2(*(const __half2*)&v2.y);
        p3 = __half22float2(*(const __half2*)&v3.y);
        a1.x += (p0.x + p1.x) + (p2.x + p3.x);
        a1.y += (p0.y + p1.y) + (p2.y + p3.y);
        p0 = __half22float2(*(const __half2*)&v0.z);
        p1 = __half22float2(*(const __half2*)&v1.z);
        p2 = __half22float2(*(const __half2*)&v2.z);
        p3 = __half22float2(*(const __half2*)&v3.z);
        a2.x += (p0.x + p1.x) + (p2.x + p3.x);
        a2.y += (p0.y + p1.y) + (p2.y + p3.y);
        p0 = __half22float2(*(const __half2*)&v0.w);
        p1 = __half22float2(*(const __half2*)&v1.w);
        p2 = __half22float2(*(const __half2*)&v2.w);
        p3 = __half22float2(*(const __half2*)&v3.w);
        a3.x += (p0.x + p1.x) + (p2.x + p3.x);
        a3.y += (p0.y + p1.y) + (p2.y + p3.y);
    }
    float dv = dinv[node];
    float4 o;
    *(__half2*)&o.x = __floats2half2_rn(dv * a0.x, dv * a0.y);
    *(__half2*)&o.y = __floats2half2_rn(dv * a1.x, dv * a1.y);
    *(__half2*)&o.z = __floats2half2_rn(dv * a2.x, dv * a2.y);
    *(__half2*)&o.w = __floats2half2_rn(dv * a3.x, dv * a3.y);
    ((float4*)p2h)[node * 2 + hf] = o;
}

// out = p2 @ W2 + b2; 32 nodes/block, thread = 4 nodes x 4 feats (f16 p2 input)
__global__ __launch_bounds__(256) void k_gemm2(const __half2* __restrict__ p2h,
                                               const float* __restrict__ W2,
                                               const float* __restrict__ b2,
                                               float* __restrict__ out) {
    __shared__ __align__(16) float w[FH * FI];
    __shared__ float pst[FH][33];                     // +1 pad: conflict-free
    float4* w4s = (float4*)w;
    w4s[threadIdx.x] = ((const float4*)W2)[threadIdx.x];
    w4s[threadIdx.x + 256] = ((const float4*)W2)[threadIdx.x + 256];
    int base = blockIdx.x * 32;
    {
        int n = threadIdx.x >> 3, cc = threadIdx.x & 7;
        int gn = base + n;
        __half2 hv = (gn < NN) ? p2h[gn * 8 + cc] : __floats2half2_rn(0.f, 0.f);
        float2 f = __half22float2(hv);
        pst[2 * cc][n]     = f.x;
        pst[2 * cc + 1][n] = f.y;
    }
    __syncthreads();
    int fg = threadIdx.x & 31;    // feature quad
    int ng = threadIdx.x >> 5;    // node group
    float4 bb = ((const float4*)b2)[fg];
    float a2[4][4];
    #pragma unroll
    for (int i = 0; i < 4; ++i) {
        a2[i][0] = bb.x; a2[i][1] = bb.y; a2[i][2] = bb.z; a2[i][3] = bb.w;
    }
    #pragma unroll
    for (int k = 0; k < FH; ++k) {
        float4 wv = w4s[k * 32 + fg];
        #pragma unroll
        for (int i = 0; i < 4; ++i) {
            float xv = pst[k][ng * 4 + i];
            a2[i][0] += xv * wv.x; a2[i][1] += xv * wv.y;
            a2[i][2] += xv * wv.z; a2[i][3] += xv * wv.w;
        }
    }
    #pragma unroll
    for (int i = 0; i < 4; ++i) {
        int gn = base + ng * 4 + i;
        if (gn < NN)
            ((float4*)out)[gn * 32 + fg] =
                make_float4(a2[i][0], a2[i][1], a2[i][2], a2[i][3]);
    }
}

extern "C" void kernel_launch(void* const* d_in, const int* in_sizes, int n_in,
                              void* d_out, int out_size, void* d_ws, size_t ws_size,
                              hipStream_t stream) {
    const float* x  = (const float*)d_in[0];
    const int*   ei = (const int*)d_in[1];
    const float* W1 = (const float*)d_in[2];
    const float* b1 = (const float*)d_in[3];
    const float* W2 = (const float*)d_in[4];
    const float* b2 = (const float*)d_in[5];
    float* out = (float*)d_out;

    const int* src = ei;
    const int* dst = ei + NE;

    // workspace layout (~18.5 MB, 4-B units).
    // csrPad = NE + 200*NB (padded buckets); hist overlays csrPad (dead by bsort);
    // g2 + p2h overlay packed (dead after bsort).
    int2*  rowSE       = (int2*)d_ws;                 // [NN]        off 0 (8B aligned)
    float* dinv        = (float*)(rowSE + NN);        // [NN]        off 200,000
    int*   totals      = (int*)(dinv + NN);           // [NB]        off 300,000
    int*   bucketStart = totals + NB;                 // [NB+1]      off 301,563
    int*   csrPad      = bucketStart + NB + 1 + 1;    // [1,912,600] off 303,128 (16B aligned)
    int*   hist        = csrPad;                      // [GC*NB]=800,256 overlay
    int*   packed      = csrPad + (NE + 200 * NB);    // [NE+16]     off 2,215,728 (16B aligned)
    __half2* g2        = (__half2*)packed;            // [(NN+1)*8] overlay
    __half2* p2h       = g2 + (NN + 1) * 8;           // [NN*8]     overlay
    __half2* g1        = (__half2*)(packed + NE + 16);// [(NN+1)*8]

    k_count_gemm1 <<<GC + (NN + 255) / 256, 256, 0, stream>>>(dst, hist, x, W1, g1);
    k_scan_chunks <<<(NB + SCB - 1) / SCB, 256, 0, stream>>>(hist, totals);
    k_scan_buckets<<<1, 1024, 0, stream>>>(totals, bucketStart, g1);
    k_scatter     <<<GC, 256, 0, stream>>>(src, dst, hist, bucketStart, packed);
    k_bsort       <<<NB, 256, 0, stream>>>(packed, bucketStart, csrPad, rowSE, dinv, g1);
    k_agg1        <<<(NN * 2 + 255) / 256, 256, 0, stream>>>(csrPad, rowSE, g1, dinv, b1, g2);
    k_agg2        <<<(NN * 2 + 255) / 256, 256, 0, stream>>>(csrPad, rowSE, g2, dinv, p2h);
    k_gemm2       <<<(NN + 31) / 32, 256, 0, stream>>>(p2h, W2, b2, out);
}